// Round 6
// baseline (96.786 us; speedup 1.0000x reference)
//
#include <hip/hip_runtime.h>
#include <hip/hip_bf16.h>

#define IMG_H 320
#define IMG_W 320
#define NPIX (IMG_H * IMG_W)
#define HID 64
#define NS 32

typedef __attribute__((ext_vector_type(8))) short short8;   // bf16 x8 (4 VGPR)
typedef __attribute__((ext_vector_type(4))) float float4v;
typedef __attribute__((ext_vector_type(4))) int   int4v;

// workspace layout (shorts): w2t[4096] | w1t[2048] | w3t[1024]  then (floats) b3pad[16]
#define W2T_OFF 0
#define W1T_OFF 4096
#define W3T_OFF (4096 + 2048)
#define B3P_FLT ((4096 + 2048 + 1024) / 2)

__device__ __forceinline__ unsigned f2bf(float f) {   // prep kernel only (cold)
    __hip_bfloat16 b = __float2bfloat16(f);
    return (unsigned)*reinterpret_cast<unsigned short*>(&b);
}

// HW packed f32->bf16 (RNE): lo16 = bf16(lo), hi16 = bf16(hi). One VALU op.
__device__ __forceinline__ unsigned cvtpk(float lo, float hi) {
    unsigned r;
    asm("v_cvt_pk_bf16_f32 %0, %1, %2" : "=v"(r) : "v"(lo), "v"(hi));
    return r;
}

// DPP add helper: x + dpp_shifted(x), 0-fill for invalid lanes / unwritten rows.
template <int CTRL, int RMASK>
__device__ __forceinline__ float dppadd(float x) {
    int s = __builtin_amdgcn_update_dpp(0, __float_as_int(x), CTRL, RMASK, 0xF, true);
    return x + __int_as_float(s);
}
// inclusive prefix sum over each 32-lane half (pure VALU, no LDS)
__device__ __forceinline__ float scan32(float x) {
    x = dppadd<0x111, 0xF>(x);   // row_shr:1
    x = dppadd<0x112, 0xF>(x);   // row_shr:2
    x = dppadd<0x114, 0xF>(x);   // row_shr:4
    x = dppadd<0x118, 0xF>(x);   // row_shr:8  -> per-16 inclusive scan
    x = dppadd<0x142, 0xA>(x);   // row_bcast:15 into rows 1,3 -> 32-inclusive
    return x;
}

// Build bf16 operand tables:
//  w1t[j][k](64x32): k<3 -> W1[k][j], k==3 -> b1[j] (bias row, B supplies 1.0), else 0
//  w2t[j][k](64x64): W2[k][j]
//  w3t[c][j](16x64): c<4 -> W3[j][c], else 0
//  b3pad[16]: b3 zero-extended (MFMA C-init for layer 3)
__global__ __launch_bounds__(256) void prep(const float* __restrict__ W1,
                                            const float* __restrict__ b1,
                                            const float* __restrict__ W2,
                                            const float* __restrict__ W3,
                                            const float* __restrict__ b3,
                                            short* __restrict__ wsS) {
    int t = threadIdx.x;
    float* wsF = reinterpret_cast<float*>(wsS);
    for (int i = t; i < 4096; i += 256) {
        int j = i >> 6, k = i & 63;
        wsS[W2T_OFF + i] = (short)f2bf(W2[k * HID + j]);
    }
    for (int i = t; i < 2048; i += 256) {
        int j = i >> 5, k = i & 31;
        float v = (k < 3) ? W1[k * HID + j] : ((k == 3) ? b1[j] : 0.0f);
        wsS[W1T_OFF + i] = (short)f2bf(v);
    }
    for (int i = t; i < 1024; i += 256) {
        int c = i >> 6, j = i & 63;
        float v = (c < 4) ? W3[j * 4 + c] : 0.0f;
        wsS[W3T_OFF + i] = (short)f2bf(v);
    }
    if (t < 16) wsF[B3P_FLT + t] = (t < 4) ? b3[t] : 0.0f;
}

__global__ __launch_bounds__(256, 2) void nerf_mfma5(
    const float* __restrict__ Kmat, const float* __restrict__ Twc,
    const float* __restrict__ aabb_min, const float* __restrict__ aabb_max,
    const short* __restrict__ ws, const float* __restrict__ b2,
    float* __restrict__ out) {
    // Conflict-free transposed h layout (per wave, dwords):
    //   hb[ ((j>>3)*64 + s)*4 + ((j>>1)&3) ] = bf16 pair (h[j],h[j+1]) for sample s.
    // LDS = exactly 32 KiB -> 5 blocks/CU (5*32768 = 163840 = full 160 KiB).
    // raw MLP outputs reuse hb after L3's reads (wave-in-order DS pipe:
    // each nt's read of [64nt,64nt+64) precedes its same-range write).
    __shared__ unsigned hbuf[4][2048];     // 32 KB total

    const int tid  = threadIdx.x;
    const int wave = tid >> 6;
    const int lane = tid & 63;
    const int l15  = lane & 15;
    const int g    = lane >> 4;

    const short* w2t = ws + W2T_OFF;
    const short* w1t = ws + W1T_OFF;
    const short* w3t = ws + W3T_OFF;
    const float* b3p = reinterpret_cast<const float*>(ws) + B3P_FLT;
    unsigned* hb = hbuf[wave];

    const int sampleId = blockIdx.x * 256 + tid;
    const int pix = sampleId >> 5;
    const int s   = sampleId & 31;

    // ---------------- ray setup (per sample; all divides -> v_rcp) ----------
    int y = pix / IMG_W, x = pix - y * IMG_W;
    float fx = Kmat[0], cx = Kmat[2], fy = Kmat[4], cy = Kmat[5];
    float u = (float)x + 0.5f, v = (float)y + 0.5f;
    float dcx = (u - cx) * __builtin_amdgcn_rcpf(fx);
    float dcy = (v - cy) * __builtin_amdgcn_rcpf(fy);
    float dcz = 1.0f;
    float inorm = rsqrtf(dcx * dcx + dcy * dcy + dcz * dcz);
    dcx *= inorm; dcy *= inorm; dcz *= inorm;
    float dx = Twc[0] * dcx + Twc[1] * dcy + Twc[2]  * dcz;
    float dy = Twc[4] * dcx + Twc[5] * dcy + Twc[6]  * dcz;
    float dz = Twc[8] * dcx + Twc[9] * dcy + Twc[10] * dcz;
    float ox = Twc[3], oy = Twc[7], oz = Twc[11];

    float mnx = aabb_min[0], mny = aabb_min[1], mnz = aabb_min[2];
    float mxx = aabb_max[0], mxy = aabb_max[1], mxz = aabb_max[2];
    float ivx = __builtin_amdgcn_rcpf(dx);
    float ivy = __builtin_amdgcn_rcpf(dy);
    float ivz = __builtin_amdgcn_rcpf(dz);
    float t1x = (mnx - ox) * ivx, t2x = (mxx - ox) * ivx;
    float t1y = (mny - oy) * ivy, t2y = (mxy - oy) * ivy;
    float t1z = (mnz - oz) * ivz, t2z = (mxz - oz) * ivz;
    float tnear = fmaxf(fmaxf(fminf(t1x, t2x), fminf(t1y, t2y)), fminf(t1z, t2z));
    float tfar  = fminf(fminf(fmaxf(t1x, t2x), fmaxf(t1y, t2y)), fmaxf(t1z, t2z));
    bool hit = tnear < tfar;
    float tn = hit ? tnear : 0.0f;
    float tf = hit ? tfar  : 1.0f;
    float step = (tf - tn) * (1.0f / NS);
    float ts = tn + (tf - tn) * (((float)s + 0.5f) * (1.0f / NS));
    float px = ox + ts * dx, py = oy + ts * dy, pz = oz + ts * dz;
    float iex = __builtin_amdgcn_rcpf(mxx - mnx);
    float iey = __builtin_amdgcn_rcpf(mxy - mny);
    float iez = __builtin_amdgcn_rcpf(mxz - mnz);
    float nx = fmaf(px - mnx, 2.0f * iex, -1.0f);
    float ny = fmaf(py - mny, 2.0f * iey, -1.0f);
    float nz = fmaf(pz - mnz, 2.0f * iez, -1.0f);

    // own sample's (x,y,z,1) packed as 4 bf16 in 2 dwords (shuffle currency)
    unsigned pd0 = cvtpk(nx, ny);
    unsigned pd1 = cvtpk(nz, 1.0f);

    // ---------------- layer 1 on MFMA: D1[j][s] = W1T(+b1 row) x [xyz;1] -----
    short8 a1[4];
#pragma unroll
    for (int mt = 0; mt < 4; ++mt)
        a1[mt] = *reinterpret_cast<const short8*>(w1t + (16 * mt + l15) * 32 + 8 * g);

    float4v acc1[4][4];
#pragma unroll
    for (int mt = 0; mt < 4; ++mt)
#pragma unroll
        for (int nt = 0; nt < 4; ++nt) acc1[mt][nt] = (float4v){0.f, 0.f, 0.f, 0.f};

#pragma unroll
    for (int nt = 0; nt < 4; ++nt) {
        int u0 = __shfl((int)pd0, 16 * nt + l15, 64);
        int u1 = __shfl((int)pd1, 16 * nt + l15, 64);
        int4v bi;
        bi[0] = (g == 0) ? u0 : 0;   // k=0..3 live only in lane-group 0
        bi[1] = (g == 0) ? u1 : 0;
        bi[2] = 0; bi[3] = 0;
        short8 bf = *reinterpret_cast<short8*>(&bi);
#pragma unroll
        for (int mt = 0; mt < 4; ++mt)
            acc1[mt][nt] = __builtin_amdgcn_mfma_f32_16x16x32_bf16(a1[mt], bf,
                                                                   acc1[mt][nt], 0, 0, 0);
    }

    // relu + HW pack + transposed store (one uint2 / tile)
    const int sstore = (g >> 1) * 64 * 4 + 2 * (g & 1);   // lane-dependent part
#pragma unroll
    for (int mt = 0; mt < 4; ++mt)
#pragma unroll
        for (int nt = 0; nt < 4; ++nt) {
            float4v a = acc1[mt][nt];
            uint2 pv;
            pv.x = cvtpk(fmaxf(a[0], 0.f), fmaxf(a[1], 0.f));
            pv.y = cvtpk(fmaxf(a[2], 0.f), fmaxf(a[3], 0.f));
            *reinterpret_cast<uint2*>(hb + (2 * mt * 64 + 16 * nt + l15) * 4 + sstore) = pv;
        }
    asm volatile("s_waitcnt lgkmcnt(0)" ::: "memory");
    __builtin_amdgcn_sched_barrier(0);

    // ---------------- layer 2 on MFMA: D2[j][s] = W2T x h1, C-init = b2 ------
    short8 a2[4][2];
#pragma unroll
    for (int mt = 0; mt < 4; ++mt)
#pragma unroll
        for (int T = 0; T < 2; ++T)
            a2[mt][T] = *reinterpret_cast<const short8*>(
                w2t + (16 * mt + l15) * HID + 32 * T + 8 * g);

    float4v acc2[4][4];
#pragma unroll
    for (int mt = 0; mt < 4; ++mt) {
        float4v bb = *reinterpret_cast<const float4v*>(b2 + 16 * mt + 4 * g);
#pragma unroll
        for (int nt = 0; nt < 4; ++nt) acc2[mt][nt] = bb;
    }

#pragma unroll
    for (int nt = 0; nt < 4; ++nt) {
        // B-frag: k-block 32T+8g, sample 16nt+l15 -> b128 of q=0..3
        short8 bf0 = *reinterpret_cast<const short8*>(hb + ((0 + g) * 64 + 16 * nt + l15) * 4);
        short8 bf1 = *reinterpret_cast<const short8*>(hb + ((4 + g) * 64 + 16 * nt + l15) * 4);
#pragma unroll
        for (int mt = 0; mt < 4; ++mt)
            acc2[mt][nt] = __builtin_amdgcn_mfma_f32_16x16x32_bf16(a2[mt][0], bf0,
                                                                   acc2[mt][nt], 0, 0, 0);
#pragma unroll
        for (int mt = 0; mt < 4; ++mt)
            acc2[mt][nt] = __builtin_amdgcn_mfma_f32_16x16x32_bf16(a2[mt][1], bf1,
                                                                   acc2[mt][nt], 0, 0, 0);
    }
    asm volatile("s_waitcnt lgkmcnt(0)" ::: "memory");   // all h1 reads drained
    __builtin_amdgcn_sched_barrier(0);

    // relu + pack + store h2 into the SAME wave-local buffer (same layout)
#pragma unroll
    for (int mt = 0; mt < 4; ++mt)
#pragma unroll
        for (int nt = 0; nt < 4; ++nt) {
            float4v a = acc2[mt][nt];
            uint2 pv;
            pv.x = cvtpk(fmaxf(a[0], 0.f), fmaxf(a[1], 0.f));
            pv.y = cvtpk(fmaxf(a[2], 0.f), fmaxf(a[3], 0.f));
            *reinterpret_cast<uint2*>(hb + (2 * mt * 64 + 16 * nt + l15) * 4 + sstore) = pv;
        }
    asm volatile("s_waitcnt lgkmcnt(0)" ::: "memory");
    __builtin_amdgcn_sched_barrier(0);

    // ---------------- layer 3 on MFMA: D3[c][s] = W3T x h2, C-init = b3pad ---
    // raw outputs reuse hb: write region [64nt,64nt+64) dwords is read (g=0,T=0)
    // in the SAME nt iteration BEFORE the write -> in-order DS pipe = safe.
    short8 a30 = *reinterpret_cast<const short8*>(w3t + l15 * HID + 8 * g);
    short8 a31 = *reinterpret_cast<const short8*>(w3t + l15 * HID + 32 + 8 * g);
    float4v ci = *reinterpret_cast<const float4v*>(b3p + 4 * g);
    float* rawf = reinterpret_cast<float*>(hb);
#pragma unroll
    for (int nt = 0; nt < 4; ++nt) {
        short8 bf0 = *reinterpret_cast<const short8*>(hb + ((0 + g) * 64 + 16 * nt + l15) * 4);
        short8 bf1 = *reinterpret_cast<const short8*>(hb + ((4 + g) * 64 + 16 * nt + l15) * 4);
        float4v dv = __builtin_amdgcn_mfma_f32_16x16x32_bf16(a30, bf0, ci, 0, 0, 0);
        dv = __builtin_amdgcn_mfma_f32_16x16x32_bf16(a31, bf1, dv, 0, 0, 0);
        if (g == 0)   // rows 0..3 = raw outputs of sample 16*nt+l15
            *reinterpret_cast<float4v*>(rawf + (16 * nt + l15) * 4) = dv;
    }
    asm volatile("s_waitcnt lgkmcnt(0)" ::: "memory");
    __builtin_amdgcn_sched_barrier(0);

    // ---------------- volume rendering (per sample; DPP scans, no LDS) -------
    float4v raw = *reinterpret_cast<const float4v*>(rawf + lane * 4);
    float r0 = raw[0], r1 = raw[1], r2 = raw[2], r3 = raw[3];

    // branchless softplus: max(x,0) + log1p(exp(-|x|))
    float sigma = fmaxf(r0, 0.0f) + __logf(1.0f + __expf(-fabsf(r0)));
    float c0 = __builtin_amdgcn_rcpf(1.0f + __expf(-r1));
    float c1 = __builtin_amdgcn_rcpf(1.0f + __expf(-r2));
    float c2 = __builtin_amdgcn_rcpf(1.0f + __expf(-r3));
    float delta = (s == NS - 1) ? 0.5f * step : step;
    float sa = sigma * delta;

    float cum = scan32(sa);                    // inclusive scan per 32-lane half
    float Tprev = __expf(-(cum - sa));
    float w = Tprev * (1.0f - __expf(-sa));
    float rr = scan32(w * c0);                 // lane31 value = full sum
    float rg = scan32(w * c1);
    float rb = scan32(w * c2);

    if (s == NS - 1) {                         // lane 31/63: holds the totals
        float alpha = 1.0f - __expf(-cum);
        float o0 = rr, o1 = rg, o2 = rb;
        if (!hit) { o0 = 0.0f; o1 = 0.0f; o2 = 0.0f; alpha = 0.0f; }
        out[0 * NPIX + pix] = o0;
        out[1 * NPIX + pix] = o1;
        out[2 * NPIX + pix] = o2;
        out[3 * NPIX + pix] = alpha;
    }
}

extern "C" void kernel_launch(void* const* d_in, const int* in_sizes, int n_in,
                              void* d_out, int out_size, void* d_ws, size_t ws_size,
                              hipStream_t stream) {
    const float* Kmat = (const float*)d_in[0];
    const float* Twc  = (const float*)d_in[1];
    const float* amn  = (const float*)d_in[2];
    const float* amx  = (const float*)d_in[3];
    const float* W1   = (const float*)d_in[4];
    const float* b1   = (const float*)d_in[5];
    const float* W2   = (const float*)d_in[6];
    const float* b2   = (const float*)d_in[7];
    const float* W3   = (const float*)d_in[8];
    const float* b3   = (const float*)d_in[9];
    float* out = (float*)d_out;
    short* ws  = (short*)d_ws;   // 14.4 KB used

    prep<<<1, 256, 0, stream>>>(W1, b1, W2, W3, b3, ws);

    int blocks = NPIX * NS / 256;   // 12,800
    nerf_mfma5<<<blocks, 256, 0, stream>>>(Kmat, Twc, amn, amx, ws, b2, out);
}

// Round 7
// 90.448 us; speedup vs baseline: 1.0701x; 1.0701x over previous
//
#include <hip/hip_runtime.h>
#include <hip/hip_bf16.h>

#define IMG_H 320
#define IMG_W 320
#define NPIX (IMG_H * IMG_W)
#define HID 64
#define NS 32

typedef __attribute__((ext_vector_type(8))) short short8;   // bf16 x8 (4 VGPR)
typedef __attribute__((ext_vector_type(4))) float float4v;
typedef __attribute__((ext_vector_type(4))) int   int4v;

// workspace layout (shorts): w2t[4096] | w1t[2048] | w3t[1024]  then (floats) b3pad[16]
#define W2T_OFF 0
#define W1T_OFF 4096
#define W3T_OFF (4096 + 2048)
#define B3P_FLT ((4096 + 2048 + 1024) / 2)

__device__ __forceinline__ unsigned f2bf(float f) {   // prep kernel only (cold)
    __hip_bfloat16 b = __float2bfloat16(f);
    return (unsigned)*reinterpret_cast<unsigned short*>(&b);
}

// HW packed f32->bf16 (RNE): lo16 = bf16(lo), hi16 = bf16(hi). One VALU op.
__device__ __forceinline__ unsigned cvtpk(float lo, float hi) {
    unsigned r;
    asm("v_cvt_pk_bf16_f32 %0, %1, %2" : "=v"(r) : "v"(lo), "v"(hi));
    return r;
}

// DPP add helper: x + dpp_shifted(x), 0-fill for invalid lanes / unwritten rows.
template <int CTRL, int RMASK>
__device__ __forceinline__ float dppadd(float x) {
    int s = __builtin_amdgcn_update_dpp(0, __float_as_int(x), CTRL, RMASK, 0xF, true);
    return x + __int_as_float(s);
}
// inclusive prefix sum over each 32-lane half (pure VALU, no LDS)
__device__ __forceinline__ float scan32(float x) {
    x = dppadd<0x111, 0xF>(x);   // row_shr:1
    x = dppadd<0x112, 0xF>(x);   // row_shr:2
    x = dppadd<0x114, 0xF>(x);   // row_shr:4
    x = dppadd<0x118, 0xF>(x);   // row_shr:8  -> per-16 inclusive scan
    x = dppadd<0x142, 0xA>(x);   // row_bcast:15 into rows 1,3 -> 32-inclusive
    return x;
}

// Build bf16 operand tables:
//  w1t[j][k](64x32): k<3 -> W1[k][j], k==3 -> b1[j] (bias row, B supplies 1.0), else 0
//  w2t[j][k](64x64): W2[k][j]
//  w3t[c][j](16x64): c<4 -> W3[j][c], else 0
//  b3pad[16]: b3 zero-extended (MFMA C-init for layer 3)
__global__ __launch_bounds__(256) void prep(const float* __restrict__ W1,
                                            const float* __restrict__ b1,
                                            const float* __restrict__ W2,
                                            const float* __restrict__ W3,
                                            const float* __restrict__ b3,
                                            short* __restrict__ wsS) {
    int t = threadIdx.x;
    float* wsF = reinterpret_cast<float*>(wsS);
    for (int i = t; i < 4096; i += 256) {
        int j = i >> 6, k = i & 63;
        wsS[W2T_OFF + i] = (short)f2bf(W2[k * HID + j]);
    }
    for (int i = t; i < 2048; i += 256) {
        int j = i >> 5, k = i & 31;
        float v = (k < 3) ? W1[k * HID + j] : ((k == 3) ? b1[j] : 0.0f);
        wsS[W1T_OFF + i] = (short)f2bf(v);
    }
    for (int i = t; i < 1024; i += 256) {
        int c = i >> 6, j = i & 63;
        float v = (c < 4) ? W3[j * 4 + c] : 0.0f;
        wsS[W3T_OFF + i] = (short)f2bf(v);
    }
    if (t < 16) wsF[B3P_FLT + t] = (t < 4) ? b3[t] : 0.0f;
}

// 128-thread blocks (2 waves): hbuf = 16 KiB/block -> ~9-10 blocks/CU
// (finer LDS granularity than the 32 KiB/block version, which capped at 4).
__global__ __launch_bounds__(128) void nerf_mfma6(
    const float* __restrict__ Kmat, const float* __restrict__ Twc,
    const float* __restrict__ aabb_min, const float* __restrict__ aabb_max,
    const short* __restrict__ ws, const float* __restrict__ b2,
    float* __restrict__ out) {
    // Conflict-free transposed h layout (per wave, dwords):
    //   hb[ ((j>>3)*64 + s)*4 + ((j>>1)&3) ] = bf16 pair (h[j],h[j+1]) for sample s.
    // Phase ordering is wave-local: the DS pipe processes one wave's LDS ops
    // in order, so the lgkmcnt(0)+"memory" asm at each phase boundary is
    // enough (it also stops the compiler from reordering provably-disjoint
    // per-thread LDS ops whose dependence is cross-lane). NO sched_barrier:
    // VALU/MFMA may schedule freely across phases.
    __shared__ unsigned hbuf[2][2048];     // 16 KiB total

    const int tid  = threadIdx.x;
    const int wave = tid >> 6;
    const int lane = tid & 63;
    const int l15  = lane & 15;
    const int g    = lane >> 4;

    const short* w2t = ws + W2T_OFF;
    const short* w1t = ws + W1T_OFF;
    const short* w3t = ws + W3T_OFF;
    const float* b3p = reinterpret_cast<const float*>(ws) + B3P_FLT;
    unsigned* hb = hbuf[wave];

    const int sampleId = blockIdx.x * 128 + tid;
    const int pix = sampleId >> 5;
    const int s   = sampleId & 31;

    // ---------------- ray setup (per sample; all divides -> v_rcp) ----------
    int y = pix / IMG_W, x = pix - y * IMG_W;
    float fx = Kmat[0], cx = Kmat[2], fy = Kmat[4], cy = Kmat[5];
    float u = (float)x + 0.5f, v = (float)y + 0.5f;
    float dcx = (u - cx) * __builtin_amdgcn_rcpf(fx);
    float dcy = (v - cy) * __builtin_amdgcn_rcpf(fy);
    float dcz = 1.0f;
    float inorm = rsqrtf(dcx * dcx + dcy * dcy + dcz * dcz);
    dcx *= inorm; dcy *= inorm; dcz *= inorm;
    float dx = Twc[0] * dcx + Twc[1] * dcy + Twc[2]  * dcz;
    float dy = Twc[4] * dcx + Twc[5] * dcy + Twc[6]  * dcz;
    float dz = Twc[8] * dcx + Twc[9] * dcy + Twc[10] * dcz;
    float ox = Twc[3], oy = Twc[7], oz = Twc[11];

    float mnx = aabb_min[0], mny = aabb_min[1], mnz = aabb_min[2];
    float mxx = aabb_max[0], mxy = aabb_max[1], mxz = aabb_max[2];
    float ivx = __builtin_amdgcn_rcpf(dx);
    float ivy = __builtin_amdgcn_rcpf(dy);
    float ivz = __builtin_amdgcn_rcpf(dz);
    float t1x = (mnx - ox) * ivx, t2x = (mxx - ox) * ivx;
    float t1y = (mny - oy) * ivy, t2y = (mxy - oy) * ivy;
    float t1z = (mnz - oz) * ivz, t2z = (mxz - oz) * ivz;
    float tnear = fmaxf(fmaxf(fminf(t1x, t2x), fminf(t1y, t2y)), fminf(t1z, t2z));
    float tfar  = fminf(fminf(fmaxf(t1x, t2x), fmaxf(t1y, t2y)), fmaxf(t1z, t2z));
    bool hit = tnear < tfar;
    float tn = hit ? tnear : 0.0f;
    float tf = hit ? tfar  : 1.0f;
    float step = (tf - tn) * (1.0f / NS);
    float ts = tn + (tf - tn) * (((float)s + 0.5f) * (1.0f / NS));
    float px = ox + ts * dx, py = oy + ts * dy, pz = oz + ts * dz;
    float iex = __builtin_amdgcn_rcpf(mxx - mnx);
    float iey = __builtin_amdgcn_rcpf(mxy - mny);
    float iez = __builtin_amdgcn_rcpf(mxz - mnz);
    float nx = fmaf(px - mnx, 2.0f * iex, -1.0f);
    float ny = fmaf(py - mny, 2.0f * iey, -1.0f);
    float nz = fmaf(pz - mnz, 2.0f * iez, -1.0f);

    // own sample's (x,y,z,1) packed as 4 bf16 in 2 dwords (shuffle currency)
    unsigned pd0 = cvtpk(nx, ny);
    unsigned pd1 = cvtpk(nz, 1.0f);

    // ---------------- layer 1 on MFMA: D1[j][s] = W1T(+b1 row) x [xyz;1] -----
    short8 a1[4];
#pragma unroll
    for (int mt = 0; mt < 4; ++mt)
        a1[mt] = *reinterpret_cast<const short8*>(w1t + (16 * mt + l15) * 32 + 8 * g);

    float4v acc1[4][4];
#pragma unroll
    for (int mt = 0; mt < 4; ++mt)
#pragma unroll
        for (int nt = 0; nt < 4; ++nt) acc1[mt][nt] = (float4v){0.f, 0.f, 0.f, 0.f};

#pragma unroll
    for (int nt = 0; nt < 4; ++nt) {
        int u0 = __shfl((int)pd0, 16 * nt + l15, 64);
        int u1 = __shfl((int)pd1, 16 * nt + l15, 64);
        int4v bi;
        bi[0] = (g == 0) ? u0 : 0;   // k=0..3 live only in lane-group 0
        bi[1] = (g == 0) ? u1 : 0;
        bi[2] = 0; bi[3] = 0;
        short8 bf = *reinterpret_cast<short8*>(&bi);
#pragma unroll
        for (int mt = 0; mt < 4; ++mt)
            acc1[mt][nt] = __builtin_amdgcn_mfma_f32_16x16x32_bf16(a1[mt], bf,
                                                                   acc1[mt][nt], 0, 0, 0);
    }

    // relu + HW pack + transposed store (one uint2 / tile)
    const int sstore = (g >> 1) * 64 * 4 + 2 * (g & 1);   // lane-dependent part
#pragma unroll
    for (int mt = 0; mt < 4; ++mt)
#pragma unroll
        for (int nt = 0; nt < 4; ++nt) {
            float4v a = acc1[mt][nt];
            uint2 pv;
            pv.x = cvtpk(fmaxf(a[0], 0.f), fmaxf(a[1], 0.f));
            pv.y = cvtpk(fmaxf(a[2], 0.f), fmaxf(a[3], 0.f));
            *reinterpret_cast<uint2*>(hb + (2 * mt * 64 + 16 * nt + l15) * 4 + sstore) = pv;
        }
    asm volatile("s_waitcnt lgkmcnt(0)" ::: "memory");

    // ---------------- layer 2 on MFMA: D2[j][s] = W2T x h1, C-init = b2 ------
    short8 a2[4][2];
#pragma unroll
    for (int mt = 0; mt < 4; ++mt)
#pragma unroll
        for (int T = 0; T < 2; ++T)
            a2[mt][T] = *reinterpret_cast<const short8*>(
                w2t + (16 * mt + l15) * HID + 32 * T + 8 * g);

    float4v acc2[4][4];
#pragma unroll
    for (int mt = 0; mt < 4; ++mt) {
        float4v bb = *reinterpret_cast<const float4v*>(b2 + 16 * mt + 4 * g);
#pragma unroll
        for (int nt = 0; nt < 4; ++nt) acc2[mt][nt] = bb;
    }

#pragma unroll
    for (int nt = 0; nt < 4; ++nt) {
        // B-frag: k-block 32T+8g, sample 16nt+l15 -> b128 of q=0..3
        short8 bf0 = *reinterpret_cast<const short8*>(hb + ((0 + g) * 64 + 16 * nt + l15) * 4);
        short8 bf1 = *reinterpret_cast<const short8*>(hb + ((4 + g) * 64 + 16 * nt + l15) * 4);
#pragma unroll
        for (int mt = 0; mt < 4; ++mt)
            acc2[mt][nt] = __builtin_amdgcn_mfma_f32_16x16x32_bf16(a2[mt][0], bf0,
                                                                   acc2[mt][nt], 0, 0, 0);
#pragma unroll
        for (int mt = 0; mt < 4; ++mt)
            acc2[mt][nt] = __builtin_amdgcn_mfma_f32_16x16x32_bf16(a2[mt][1], bf1,
                                                                   acc2[mt][nt], 0, 0, 0);
    }
    asm volatile("s_waitcnt lgkmcnt(0)" ::: "memory");   // all h1 reads drained

    // relu + pack + store h2 into the SAME wave-local buffer (same layout)
#pragma unroll
    for (int mt = 0; mt < 4; ++mt)
#pragma unroll
        for (int nt = 0; nt < 4; ++nt) {
            float4v a = acc2[mt][nt];
            uint2 pv;
            pv.x = cvtpk(fmaxf(a[0], 0.f), fmaxf(a[1], 0.f));
            pv.y = cvtpk(fmaxf(a[2], 0.f), fmaxf(a[3], 0.f));
            *reinterpret_cast<uint2*>(hb + (2 * mt * 64 + 16 * nt + l15) * 4 + sstore) = pv;
        }
    asm volatile("s_waitcnt lgkmcnt(0)" ::: "memory");

    // ---------------- layer 3 on MFMA: D3[c][s] = W3T x h2, C-init = b3pad ---
    // raw outputs reuse hb: write region [64nt,64nt+64) dwords is read (g=0,T=0)
    // in the SAME nt iteration BEFORE the write -> in-order DS pipe = safe.
    short8 a30 = *reinterpret_cast<const short8*>(w3t + l15 * HID + 8 * g);
    short8 a31 = *reinterpret_cast<const short8*>(w3t + l15 * HID + 32 + 8 * g);
    float4v ci = *reinterpret_cast<const float4v*>(b3p + 4 * g);
    float* rawf = reinterpret_cast<float*>(hb);
#pragma unroll
    for (int nt = 0; nt < 4; ++nt) {
        short8 bf0 = *reinterpret_cast<const short8*>(hb + ((0 + g) * 64 + 16 * nt + l15) * 4);
        short8 bf1 = *reinterpret_cast<const short8*>(hb + ((4 + g) * 64 + 16 * nt + l15) * 4);
        float4v dv = __builtin_amdgcn_mfma_f32_16x16x32_bf16(a30, bf0, ci, 0, 0, 0);
        dv = __builtin_amdgcn_mfma_f32_16x16x32_bf16(a31, bf1, dv, 0, 0, 0);
        if (g == 0)   // rows 0..3 = raw outputs of sample 16*nt+l15
            *reinterpret_cast<float4v*>(rawf + (16 * nt + l15) * 4) = dv;
    }
    asm volatile("s_waitcnt lgkmcnt(0)" ::: "memory");

    // ---------------- volume rendering (per sample; DPP scans, no LDS) -------
    float4v raw = *reinterpret_cast<const float4v*>(rawf + lane * 4);
    float r0 = raw[0], r1 = raw[1], r2 = raw[2], r3 = raw[3];

    // branchless softplus: max(x,0) + log1p(exp(-|x|))
    float sigma = fmaxf(r0, 0.0f) + __logf(1.0f + __expf(-fabsf(r0)));
    float c0 = __builtin_amdgcn_rcpf(1.0f + __expf(-r1));
    float c1 = __builtin_amdgcn_rcpf(1.0f + __expf(-r2));
    float c2 = __builtin_amdgcn_rcpf(1.0f + __expf(-r3));
    float delta = (s == NS - 1) ? 0.5f * step : step;
    float sa = sigma * delta;

    float cum = scan32(sa);                    // inclusive scan per 32-lane half
    float Tprev = __expf(-(cum - sa));
    float w = Tprev * (1.0f - __expf(-sa));
    float rr = scan32(w * c0);                 // lane31 value = full sum
    float rg = scan32(w * c1);
    float rb = scan32(w * c2);

    if (s == NS - 1) {                         // lane 31/63: holds the totals
        float alpha = 1.0f - __expf(-cum);
        float o0 = rr, o1 = rg, o2 = rb;
        if (!hit) { o0 = 0.0f; o1 = 0.0f; o2 = 0.0f; alpha = 0.0f; }
        out[0 * NPIX + pix] = o0;
        out[1 * NPIX + pix] = o1;
        out[2 * NPIX + pix] = o2;
        out[3 * NPIX + pix] = alpha;
    }
}

extern "C" void kernel_launch(void* const* d_in, const int* in_sizes, int n_in,
                              void* d_out, int out_size, void* d_ws, size_t ws_size,
                              hipStream_t stream) {
    const float* Kmat = (const float*)d_in[0];
    const float* Twc  = (const float*)d_in[1];
    const float* amn  = (const float*)d_in[2];
    const float* amx  = (const float*)d_in[3];
    const float* W1   = (const float*)d_in[4];
    const float* b1   = (const float*)d_in[5];
    const float* W2   = (const float*)d_in[6];
    const float* b2   = (const float*)d_in[7];
    const float* W3   = (const float*)d_in[8];
    const float* b3   = (const float*)d_in[9];
    float* out = (float*)d_out;
    short* ws  = (short*)d_ws;   // 14.4 KB used

    prep<<<1, 256, 0, stream>>>(W1, b1, W2, W3, b3, ws);

    int blocks = NPIX * NS / 128;   // 25,600
    nerf_mfma6<<<blocks, 128, 0, stream>>>(Kmat, Twc, amn, amx, ws, b2, out);
}

// Round 8
// 74.728 us; speedup vs baseline: 1.2952x; 1.2104x over previous
//
#include <hip/hip_runtime.h>
#include <hip/hip_bf16.h>

#define IMG_H 320
#define IMG_W 320
#define NPIX (IMG_H * IMG_W)
#define HID 64
#define NS 32

typedef __attribute__((ext_vector_type(8))) short short8;   // bf16 x8 (4 VGPR)
typedef __attribute__((ext_vector_type(4))) float float4v;
typedef __attribute__((ext_vector_type(4))) int   int4v;

// workspace layout (shorts): w2t[4096] | w1t[2048] | w3t[1024]  then (floats) b3pad[16]
#define W2T_OFF 0
#define W1T_OFF 4096
#define W3T_OFF (4096 + 2048)
#define B3P_FLT ((4096 + 2048 + 1024) / 2)

__device__ __forceinline__ unsigned f2bf(float f) {   // prep kernel only (cold)
    __hip_bfloat16 b = __float2bfloat16(f);
    return (unsigned)*reinterpret_cast<unsigned short*>(&b);
}

// HW packed f32->bf16 (RNE): lo16 = bf16(lo), hi16 = bf16(hi). One VALU op.
__device__ __forceinline__ unsigned cvtpk(float lo, float hi) {
    unsigned r;
    asm("v_cvt_pk_bf16_f32 %0, %1, %2" : "=v"(r) : "v"(lo), "v"(hi));
    return r;
}

// relu + pack two D-fragments (lo-half, hi-half) into the next layer's
// B-fragment: element e = 4*half + r  ->  dwords (e=2w,2w+1).
__device__ __forceinline__ short8 packfrag(float4v lo, float4v hi) {
    int4v p;
    p[0] = (int)cvtpk(fmaxf(lo[0], 0.f), fmaxf(lo[1], 0.f));
    p[1] = (int)cvtpk(fmaxf(lo[2], 0.f), fmaxf(lo[3], 0.f));
    p[2] = (int)cvtpk(fmaxf(hi[0], 0.f), fmaxf(hi[1], 0.f));
    p[3] = (int)cvtpk(fmaxf(hi[2], 0.f), fmaxf(hi[3], 0.f));
    return *reinterpret_cast<short8*>(&p);
}

// DPP add helper + 32-lane inclusive scan (pure VALU, no LDS)
template <int CTRL, int RMASK>
__device__ __forceinline__ float dppadd(float x) {
    int s = __builtin_amdgcn_update_dpp(0, __float_as_int(x), CTRL, RMASK, 0xF, true);
    return x + __int_as_float(s);
}
__device__ __forceinline__ float scan32(float x) {
    x = dppadd<0x111, 0xF>(x);   // row_shr:1
    x = dppadd<0x112, 0xF>(x);   // row_shr:2
    x = dppadd<0x114, 0xF>(x);   // row_shr:4
    x = dppadd<0x118, 0xF>(x);   // row_shr:8
    x = dppadd<0x142, 0xA>(x);   // row_bcast:15 into rows 1,3
    return x;
}

// Layout-fused weight tables. KEY IDEA: MFMA D-layout puts row m=4g+r in
// lane(g,l15); the NEXT layer's B-fragment wants j=32T+8g+(4*half+r) there.
// So A-tile (T,half) row m holds W^T row j(m) = 32T + 8(m>>2) + 4*half + (m&3)
// -> each layer's MFMA output IS the next layer's B-fragment (after
// relu+cvt_pk in registers). No LDS transpose round-trips.
//  w1t[t=(T,half)][m][k] (4x16x32): k<3 -> W1[k][j(t,m)], k==3 -> b1[j(t,m)], else 0
//  w2t[i=((T3,half),T2)][m][k2] (8x16x32): W2[32*T2+k2][j(T3,half,m)]
//  w3t[c][j] (16x64): c<4 -> W3[j][c], else 0
//  b3pad[16]: b3 zero-extended
__global__ __launch_bounds__(256) void prep(const float* __restrict__ W1,
                                            const float* __restrict__ b1,
                                            const float* __restrict__ W2,
                                            const float* __restrict__ W3,
                                            const float* __restrict__ b3,
                                            short* __restrict__ wsS) {
    int t = threadIdx.x;
    float* wsF = reinterpret_cast<float*>(wsS);
    for (int i = t; i < 4096; i += 256) {          // w2t
        int idx = i >> 9, m = (i >> 5) & 15, k2 = i & 31;
        int j3 = 32 * (idx >> 2) + 8 * (m >> 2) + 4 * ((idx >> 1) & 1) + (m & 3);
        int k  = 32 * (idx & 1) + k2;
        wsS[W2T_OFF + i] = (short)f2bf(W2[k * HID + j3]);
    }
    for (int i = t; i < 2048; i += 256) {          // w1t
        int tt = i >> 9, m = (i >> 5) & 15, k = i & 31;
        int j = 32 * (tt >> 1) + 8 * (m >> 2) + 4 * (tt & 1) + (m & 3);
        float v = (k < 3) ? W1[k * HID + j] : ((k == 3) ? b1[j] : 0.0f);
        wsS[W1T_OFF + i] = (short)f2bf(v);
    }
    for (int i = t; i < 1024; i += 256) {          // w3t
        int c = i >> 6, j = i & 63;
        float v = (c < 4) ? W3[j * 4 + c] : 0.0f;
        wsS[W3T_OFF + i] = (short)f2bf(v);
    }
    if (t < 16) wsF[B3P_FLT + t] = (t < 4) ? b3[t] : 0.0f;
}

__global__ __launch_bounds__(256, 2) void nerf_reg(
    const float* __restrict__ Kmat, const float* __restrict__ Twc,
    const float* __restrict__ aabb_min, const float* __restrict__ aabb_max,
    const short* __restrict__ ws, const float* __restrict__ b2,
    float* __restrict__ out) {
    // Only LDS use: 1 KB/wave staging to route raw MLP outputs (held by g==0
    // lanes, sample-major) to render lanes. All layer-to-layer data is in
    // registers. No __syncthreads anywhere (wave-local exchange only).
    __shared__ float rawLds[4][256];   // 4 KB/block

    const int tid  = threadIdx.x;
    const int wave = tid >> 6;
    const int lane = tid & 63;
    const int l15  = lane & 15;
    const int g    = lane >> 4;

    const short* w2t = ws + W2T_OFF;
    const short* w1t = ws + W1T_OFF;
    const short* w3t = ws + W3T_OFF;
    const float* b3p = reinterpret_cast<const float*>(ws) + B3P_FLT;
    float* rawf = rawLds[wave];

    const int sampleId = blockIdx.x * 256 + tid;
    const int pix = sampleId >> 5;
    const int s   = sampleId & 31;

    // ---------------- ray setup (per sample; divides -> v_rcp) --------------
    int y = pix / IMG_W, x = pix - y * IMG_W;
    float fx = Kmat[0], cx = Kmat[2], fy = Kmat[4], cy = Kmat[5];
    float u = (float)x + 0.5f, v = (float)y + 0.5f;
    float dcx = (u - cx) * __builtin_amdgcn_rcpf(fx);
    float dcy = (v - cy) * __builtin_amdgcn_rcpf(fy);
    float dcz = 1.0f;
    float inorm = rsqrtf(dcx * dcx + dcy * dcy + dcz * dcz);
    dcx *= inorm; dcy *= inorm; dcz *= inorm;
    float dx = Twc[0] * dcx + Twc[1] * dcy + Twc[2]  * dcz;
    float dy = Twc[4] * dcx + Twc[5] * dcy + Twc[6]  * dcz;
    float dz = Twc[8] * dcx + Twc[9] * dcy + Twc[10] * dcz;
    float ox = Twc[3], oy = Twc[7], oz = Twc[11];

    float mnx = aabb_min[0], mny = aabb_min[1], mnz = aabb_min[2];
    float mxx = aabb_max[0], mxy = aabb_max[1], mxz = aabb_max[2];
    float ivx = __builtin_amdgcn_rcpf(dx);
    float ivy = __builtin_amdgcn_rcpf(dy);
    float ivz = __builtin_amdgcn_rcpf(dz);
    float t1x = (mnx - ox) * ivx, t2x = (mxx - ox) * ivx;
    float t1y = (mny - oy) * ivy, t2y = (mxy - oy) * ivy;
    float t1z = (mnz - oz) * ivz, t2z = (mxz - oz) * ivz;
    float tnear = fmaxf(fmaxf(fminf(t1x, t2x), fminf(t1y, t2y)), fminf(t1z, t2z));
    float tfar  = fminf(fminf(fmaxf(t1x, t2x), fmaxf(t1y, t2y)), fmaxf(t1z, t2z));
    bool hit = tnear < tfar;
    float tn = hit ? tnear : 0.0f;
    float tf = hit ? tfar  : 1.0f;
    float step = (tf - tn) * (1.0f / NS);
    float ts = tn + (tf - tn) * (((float)s + 0.5f) * (1.0f / NS));
    float px = ox + ts * dx, py = oy + ts * dy, pz = oz + ts * dz;
    float iex = __builtin_amdgcn_rcpf(mxx - mnx);
    float iey = __builtin_amdgcn_rcpf(mxy - mny);
    float iez = __builtin_amdgcn_rcpf(mxz - mnz);
    float nx = fmaf(px - mnx, 2.0f * iex, -1.0f);
    float ny = fmaf(py - mny, 2.0f * iey, -1.0f);
    float nz = fmaf(pz - mnz, 2.0f * iez, -1.0f);

    // own sample's (x,y,z,1) packed as 4 bf16 in 2 dwords (shuffle currency)
    unsigned pd0 = cvtpk(nx, ny);
    unsigned pd1 = cvtpk(nz, 1.0f);

    // ---------------- weight fragments (global, L2-resident, hoisted) -------
    short8 a1[4];
#pragma unroll
    for (int t = 0; t < 4; ++t)
        a1[t] = *reinterpret_cast<const short8*>(w1t + (t * 16 + l15) * 32 + 8 * g);
    short8 a2[8];
#pragma unroll
    for (int i = 0; i < 8; ++i)
        a2[i] = *reinterpret_cast<const short8*>(w2t + (i * 16 + l15) * 32 + 8 * g);
    short8 a3[2];
#pragma unroll
    for (int T3 = 0; T3 < 2; ++T3)
        a3[T3] = *reinterpret_cast<const short8*>(w3t + l15 * HID + 32 * T3 + 8 * g);
    float4v binit[4];
#pragma unroll
    for (int uu = 0; uu < 4; ++uu)   // C-init for L2 tile u=(T3,half): b2[j3(r=0..3)]
        binit[uu] = *reinterpret_cast<const float4v*>(
            b2 + 32 * (uu >> 1) + 4 * (uu & 1) + 8 * g);
    float4v ci = *reinterpret_cast<const float4v*>(b3p + 4 * g);

    // ---------------- fused 3-layer MLP, all in registers -------------------
#pragma unroll
    for (int nt = 0; nt < 4; ++nt) {
        // L1 B-operand: (x,y,z,1) of samples 16nt+l15 in k=0..3 (lane-group 0)
        int u0 = __shfl((int)pd0, 16 * nt + l15, 64);
        int u1 = __shfl((int)pd1, 16 * nt + l15, 64);
        int4v bi;
        bi[0] = (g == 0) ? u0 : 0;
        bi[1] = (g == 0) ? u1 : 0;
        bi[2] = 0; bi[3] = 0;
        short8 bx = *reinterpret_cast<short8*>(&bi);

        // L1: 4 row-permuted tiles -> D1 is L2's B-fragment layout
        float4v c1[4];
#pragma unroll
        for (int t = 0; t < 4; ++t)
            c1[t] = __builtin_amdgcn_mfma_f32_16x16x32_bf16(
                a1[t], bx, (float4v){0.f, 0.f, 0.f, 0.f}, 0, 0, 0);
        short8 pa0 = packfrag(c1[0], c1[1]);   // k = 0..31  of h1
        short8 pa1 = packfrag(c1[2], c1[3]);   // k = 32..63 of h1

        // L2: 4 row-permuted output tiles x 2 K-chunks, C-init = b2
        float4v c2[4];
#pragma unroll
        for (int uu = 0; uu < 4; ++uu) c2[uu] = binit[uu];
#pragma unroll
        for (int uu = 0; uu < 4; ++uu)
            c2[uu] = __builtin_amdgcn_mfma_f32_16x16x32_bf16(a2[uu * 2 + 0], pa0,
                                                             c2[uu], 0, 0, 0);
#pragma unroll
        for (int uu = 0; uu < 4; ++uu)
            c2[uu] = __builtin_amdgcn_mfma_f32_16x16x32_bf16(a2[uu * 2 + 1], pa1,
                                                             c2[uu], 0, 0, 0);
        short8 pb0 = packfrag(c2[0], c2[1]);   // k = 0..31  of h2
        short8 pb1 = packfrag(c2[2], c2[3]);   // k = 32..63 of h2

        // L3: raw outputs (rows 0..3 live at lane-group 0), C-init = b3pad
        float4v dv = __builtin_amdgcn_mfma_f32_16x16x32_bf16(a3[0], pb0, ci, 0, 0, 0);
        dv = __builtin_amdgcn_mfma_f32_16x16x32_bf16(a3[1], pb1, dv, 0, 0, 0);
        if (g == 0)
            *reinterpret_cast<float4v*>(rawf + (16 * nt + l15) * 4) = dv;
    }
    // writes (g==0 lanes) -> reads (all lanes) is cross-lane: fence so the
    // compiler can't reorder, HW DS pipe is wave-in-order.
    asm volatile("s_waitcnt lgkmcnt(0)" ::: "memory");

    // ---------------- volume rendering (per sample; DPP scans) --------------
    float4v raw = *reinterpret_cast<const float4v*>(rawf + lane * 4);
    float r0 = raw[0], r1 = raw[1], r2 = raw[2], r3 = raw[3];

    float sigma = fmaxf(r0, 0.0f) + __logf(1.0f + __expf(-fabsf(r0)));
    float c0 = __builtin_amdgcn_rcpf(1.0f + __expf(-r1));
    float c1 = __builtin_amdgcn_rcpf(1.0f + __expf(-r2));
    float c2 = __builtin_amdgcn_rcpf(1.0f + __expf(-r3));
    float delta = (s == NS - 1) ? 0.5f * step : step;
    float sa = sigma * delta;

    float cum = scan32(sa);
    float Tprev = __expf(-(cum - sa));
    float w = Tprev * (1.0f - __expf(-sa));
    float rr = scan32(w * c0);
    float rg = scan32(w * c1);
    float rb = scan32(w * c2);

    if (s == NS - 1) {                         // lane 31/63 holds the totals
        float alpha = 1.0f - __expf(-cum);
        float o0 = rr, o1 = rg, o2 = rb;
        if (!hit) { o0 = 0.0f; o1 = 0.0f; o2 = 0.0f; alpha = 0.0f; }
        out[0 * NPIX + pix] = o0;
        out[1 * NPIX + pix] = o1;
        out[2 * NPIX + pix] = o2;
        out[3 * NPIX + pix] = alpha;
    }
}

extern "C" void kernel_launch(void* const* d_in, const int* in_sizes, int n_in,
                              void* d_out, int out_size, void* d_ws, size_t ws_size,
                              hipStream_t stream) {
    const float* Kmat = (const float*)d_in[0];
    const float* Twc  = (const float*)d_in[1];
    const float* amn  = (const float*)d_in[2];
    const float* amx  = (const float*)d_in[3];
    const float* W1   = (const float*)d_in[4];
    const float* b1   = (const float*)d_in[5];
    const float* W2   = (const float*)d_in[6];
    const float* b2   = (const float*)d_in[7];
    const float* W3   = (const float*)d_in[8];
    const float* b3   = (const float*)d_in[9];
    float* out = (float*)d_out;
    short* ws  = (short*)d_ws;   // 14.4 KB used

    prep<<<1, 256, 0, stream>>>(W1, b1, W2, W3, b3, ws);

    int blocks = NPIX * NS / 256;   // 12,800
    nerf_reg<<<blocks, 256, 0, stream>>>(Kmat, Twc, amn, amx, ws, b2, out);
}

// Round 9
// 70.229 us; speedup vs baseline: 1.3781x; 1.0641x over previous
//
#include <hip/hip_runtime.h>
#include <hip/hip_bf16.h>

#define IMG_H 320
#define IMG_W 320
#define NPIX (IMG_H * IMG_W)
#define HID 64
#define NS 32

typedef __attribute__((ext_vector_type(8))) short short8;   // bf16 x8 (4 VGPR)
typedef __attribute__((ext_vector_type(4))) float float4v;
typedef __attribute__((ext_vector_type(4))) int   int4v;

// ws layout (shorts): w2t[4096] | w1t[2048] | w3t[1024] ; floats: b3pad[16] | b2[64] | zpad
// byte size used: 15360 (15 x 1KB chunks, zero-padded) -- ws_size >= 16 KB (round-1 used 16 KB).
#define W2T_OFF 0
#define W1T_OFF 4096
#define W3T_OFF (4096 + 2048)
#define B3P_FLT 3584            // float index of b3pad (byte 14336)
#define B2_FLT  3600            // float index of b2 copy (byte 14400)
#define WS_BYTES 15360

__device__ __forceinline__ unsigned f2bf(float f) {   // prep kernel only (cold)
    __hip_bfloat16 b = __float2bfloat16(f);
    return (unsigned)*reinterpret_cast<unsigned short*>(&b);
}

// HW packed f32->bf16 (RNE): lo16 = bf16(lo), hi16 = bf16(hi). One VALU op.
__device__ __forceinline__ unsigned cvtpk(float lo, float hi) {
    unsigned r;
    asm("v_cvt_pk_bf16_f32 %0, %1, %2" : "=v"(r) : "v"(lo), "v"(hi));
    return r;
}

// relu + pack two D-fragments (lo-half, hi-half) into the next layer's B-fragment.
__device__ __forceinline__ short8 packfrag(float4v lo, float4v hi) {
    int4v p;
    p[0] = (int)cvtpk(fmaxf(lo[0], 0.f), fmaxf(lo[1], 0.f));
    p[1] = (int)cvtpk(fmaxf(lo[2], 0.f), fmaxf(lo[3], 0.f));
    p[2] = (int)cvtpk(fmaxf(hi[0], 0.f), fmaxf(hi[1], 0.f));
    p[3] = (int)cvtpk(fmaxf(hi[2], 0.f), fmaxf(hi[3], 0.f));
    return *reinterpret_cast<short8*>(&p);
}

// DPP add helper + 32-lane inclusive scan (pure VALU, no LDS)
template <int CTRL, int RMASK>
__device__ __forceinline__ float dppadd(float x) {
    int s = __builtin_amdgcn_update_dpp(0, __float_as_int(x), CTRL, RMASK, 0xF, true);
    return x + __int_as_float(s);
}
__device__ __forceinline__ float scan32(float x) {
    x = dppadd<0x111, 0xF>(x);   // row_shr:1
    x = dppadd<0x112, 0xF>(x);   // row_shr:2
    x = dppadd<0x114, 0xF>(x);   // row_shr:4
    x = dppadd<0x118, 0xF>(x);   // row_shr:8
    x = dppadd<0x142, 0xA>(x);   // row_bcast:15 into rows 1,3
    return x;
}

// async global->LDS, 16B per lane (dest = uniform base + lane*16)
__device__ __forceinline__ void gload_lds16(const void* g, void* l) {
    __builtin_amdgcn_global_load_lds(
        (const __attribute__((address_space(1))) unsigned int*)g,
        (__attribute__((address_space(3))) unsigned int*)l, 16, 0, 0);
}

// Layout-fused weight tables (same permutation as round 8: MFMA D-row m=4g+r in
// lane(g,l15) IS the next layer's B-frag j=32T+8g+(4*half+r) after the baked
// row reorder j(t,m) = 32T + 8(m>>2) + 4*half + (m&3)).
__global__ __launch_bounds__(256) void prep(const float* __restrict__ W1,
                                            const float* __restrict__ b1,
                                            const float* __restrict__ W2,
                                            const float* __restrict__ W3,
                                            const float* __restrict__ b3,
                                            const float* __restrict__ b2,
                                            short* __restrict__ wsS) {
    int t = threadIdx.x;
    float* wsF = reinterpret_cast<float*>(wsS);
    for (int i = t; i < 4096; i += 256) {          // w2t
        int idx = i >> 9, m = (i >> 5) & 15, k2 = i & 31;
        int j3 = 32 * (idx >> 2) + 8 * (m >> 2) + 4 * ((idx >> 1) & 1) + (m & 3);
        int k  = 32 * (idx & 1) + k2;
        wsS[W2T_OFF + i] = (short)f2bf(W2[k * HID + j3]);
    }
    for (int i = t; i < 2048; i += 256) {          // w1t
        int tt = i >> 9, m = (i >> 5) & 15, k = i & 31;
        int j = 32 * (tt >> 1) + 8 * (m >> 2) + 4 * (tt & 1) + (m & 3);
        float v = (k < 3) ? W1[k * HID + j] : ((k == 3) ? b1[j] : 0.0f);
        wsS[W1T_OFF + i] = (short)f2bf(v);
    }
    for (int i = t; i < 1024; i += 256) {          // w3t
        int c = i >> 6, j = i & 63;
        float v = (c < 4) ? W3[j * 4 + c] : 0.0f;
        wsS[W3T_OFF + i] = (short)f2bf(v);
    }
    if (t < 16) wsF[B3P_FLT + t] = (t < 4) ? b3[t] : 0.0f;
    if (t < 64) wsF[B2_FLT + t] = b2[t];
    for (int i = t; i < (WS_BYTES / 4) - (B2_FLT + 64); i += 256)   // zero pad
        wsF[B2_FLT + 64 + i] = 0.0f;
}

__global__ __launch_bounds__(256, 2) void nerf_reg2(
    const float* __restrict__ Kmat, const float* __restrict__ Twc,
    const float* __restrict__ aabb_min, const float* __restrict__ aabb_max,
    const short* __restrict__ ws, float* __restrict__ out) {
    // LDS: weight tables (block-shared, copied once) + per-pixel ray params +
    // per-wave raw-output staging. One __syncthreads after the copy/setup
    // phase; everything after is wave-local (lgkm fences only).
    __shared__ __align__(16) short wlds[WS_BYTES / 2];   // 15360 B
    __shared__ __align__(16) float pp[8][12];            // 384 B
    __shared__ __align__(16) float rawLds[4][256];       // 4 KB

    const int tid  = threadIdx.x;
    const int wave = tid >> 6;
    const int lane = tid & 63;
    const int l15  = lane & 15;
    const int g    = lane >> 4;

    // ---- issue async weight copy first (latency hides under setup) ----
    {
        const char* wsb = (const char*)ws;
        char* wl = (char*)wlds;
        for (int c = wave; c < WS_BYTES / 1024; c += 4)
            gload_lds16(wsb + c * 1024 + lane * 16, wl + c * 1024);
    }

    // ---- per-pixel ray setup: lanes 0..7 of wave 0 only ----
    if (tid < 8) {
        int p = blockIdx.x * 8 + tid;
        int y = p / IMG_W, x = p - y * IMG_W;
        float fx = Kmat[0], cx = Kmat[2], fy = Kmat[4], cy = Kmat[5];
        float u = (float)x + 0.5f, v = (float)y + 0.5f;
        float dcx = (u - cx) * __builtin_amdgcn_rcpf(fx);
        float dcy = (v - cy) * __builtin_amdgcn_rcpf(fy);
        float dcz = 1.0f;
        float inorm = rsqrtf(dcx * dcx + dcy * dcy + dcz * dcz);
        dcx *= inorm; dcy *= inorm; dcz *= inorm;
        float dx = Twc[0] * dcx + Twc[1] * dcy + Twc[2]  * dcz;
        float dy = Twc[4] * dcx + Twc[5] * dcy + Twc[6]  * dcz;
        float dz = Twc[8] * dcx + Twc[9] * dcy + Twc[10] * dcz;
        float ox = Twc[3], oy = Twc[7], oz = Twc[11];

        float mnx = aabb_min[0], mny = aabb_min[1], mnz = aabb_min[2];
        float mxx = aabb_max[0], mxy = aabb_max[1], mxz = aabb_max[2];
        float ivx = __builtin_amdgcn_rcpf(dx);
        float ivy = __builtin_amdgcn_rcpf(dy);
        float ivz = __builtin_amdgcn_rcpf(dz);
        float t1x = (mnx - ox) * ivx, t2x = (mxx - ox) * ivx;
        float t1y = (mny - oy) * ivy, t2y = (mxy - oy) * ivy;
        float t1z = (mnz - oz) * ivz, t2z = (mxz - oz) * ivz;
        float tnear = fmaxf(fmaxf(fminf(t1x, t2x), fminf(t1y, t2y)), fminf(t1z, t2z));
        float tfar  = fminf(fminf(fmaxf(t1x, t2x), fmaxf(t1y, t2y)), fmaxf(t1z, t2z));
        bool hit = tnear < tfar;
        float tn = hit ? tnear : 0.0f;
        float tf = hit ? tfar  : 1.0f;
        float step = (tf - tn) * (1.0f / NS);
        float iex = 2.0f * __builtin_amdgcn_rcpf(mxx - mnx);
        float iey = 2.0f * __builtin_amdgcn_rcpf(mxy - mny);
        float iez = 2.0f * __builtin_amdgcn_rcpf(mxz - mnz);
        pp[tid][0] = dx * iex;                    // Ax
        pp[tid][1] = dy * iey;                    // Ay
        pp[tid][2] = dz * iez;                    // Az
        pp[tid][3] = (ox - mnx) * iex - 1.0f;     // Bx
        pp[tid][4] = (oy - mny) * iey - 1.0f;     // By
        pp[tid][5] = (oz - mnz) * iez - 1.0f;     // Bz
        pp[tid][6] = tn;
        pp[tid][7] = step;
        pp[tid][8] = hit ? 1.0f : 0.0f;
    }
    __syncthreads();   // weights in LDS + pp visible to all waves

    const short* w2l = wlds + W2T_OFF;
    const short* w1l = wlds + W1T_OFF;
    const short* w3l = wlds + W3T_OFF;
    const float* bpf = reinterpret_cast<const float*>(wlds);
    float* rawf = rawLds[wave];

    const int s  = tid & 31;                 // sample index within pixel
    const int lp = (tid >> 5) & 7;           // local pixel

    // ---- per-sample position from per-pixel params (a few fma) ----
    float4v P0 = *reinterpret_cast<const float4v*>(&pp[lp][0]);  // Ax,Ay,Az,Bx
    float4v P1 = *reinterpret_cast<const float4v*>(&pp[lp][4]);  // By,Bz,tn,step
    float hitf = pp[lp][8];
    float step = P1[3];
    float tsv  = fmaf(step, (float)s + 0.5f, P1[2]);
    float nx = fmaf(tsv, P0[0], P0[3]);
    float ny = fmaf(tsv, P0[1], P1[0]);
    float nz = fmaf(tsv, P0[2], P1[1]);

    unsigned pd0 = cvtpk(nx, ny);
    unsigned pd1 = cvtpk(nz, 1.0f);

    // ---- weight fragments from LDS (cheap re-reads; compiler hoists) ----
    short8 a1[4];
#pragma unroll
    for (int t = 0; t < 4; ++t)
        a1[t] = *reinterpret_cast<const short8*>(w1l + (t * 16 + l15) * 32 + 8 * g);
    short8 a2[8];
#pragma unroll
    for (int i = 0; i < 8; ++i)
        a2[i] = *reinterpret_cast<const short8*>(w2l + (i * 16 + l15) * 32 + 8 * g);
    short8 a3[2];
#pragma unroll
    for (int T3 = 0; T3 < 2; ++T3)
        a3[T3] = *reinterpret_cast<const short8*>(w3l + l15 * HID + 32 * T3 + 8 * g);
    float4v binit[4];
#pragma unroll
    for (int uu = 0; uu < 4; ++uu)
        binit[uu] = *reinterpret_cast<const float4v*>(
            bpf + B2_FLT + 32 * (uu >> 1) + 4 * (uu & 1) + 8 * g);
    float4v ci = *reinterpret_cast<const float4v*>(bpf + B3P_FLT + 4 * g);

    // ---- fused 3-layer MLP, all in registers ----
#pragma unroll
    for (int nt = 0; nt < 4; ++nt) {
        int u0 = __shfl((int)pd0, 16 * nt + l15, 64);
        int u1 = __shfl((int)pd1, 16 * nt + l15, 64);
        int4v bi;
        bi[0] = (g == 0) ? u0 : 0;
        bi[1] = (g == 0) ? u1 : 0;
        bi[2] = 0; bi[3] = 0;
        short8 bx = *reinterpret_cast<short8*>(&bi);

        float4v c1[4];
#pragma unroll
        for (int t = 0; t < 4; ++t)
            c1[t] = __builtin_amdgcn_mfma_f32_16x16x32_bf16(
                a1[t], bx, (float4v){0.f, 0.f, 0.f, 0.f}, 0, 0, 0);
        short8 pa0 = packfrag(c1[0], c1[1]);
        short8 pa1 = packfrag(c1[2], c1[3]);

        float4v c2[4];
#pragma unroll
        for (int uu = 0; uu < 4; ++uu) c2[uu] = binit[uu];
#pragma unroll
        for (int uu = 0; uu < 4; ++uu)
            c2[uu] = __builtin_amdgcn_mfma_f32_16x16x32_bf16(a2[uu * 2 + 0], pa0,
                                                             c2[uu], 0, 0, 0);
#pragma unroll
        for (int uu = 0; uu < 4; ++uu)
            c2[uu] = __builtin_amdgcn_mfma_f32_16x16x32_bf16(a2[uu * 2 + 1], pa1,
                                                             c2[uu], 0, 0, 0);
        short8 pb0 = packfrag(c2[0], c2[1]);
        short8 pb1 = packfrag(c2[2], c2[3]);

        float4v dv = __builtin_amdgcn_mfma_f32_16x16x32_bf16(a3[0], pb0, ci, 0, 0, 0);
        dv = __builtin_amdgcn_mfma_f32_16x16x32_bf16(a3[1], pb1, dv, 0, 0, 0);
        if (g == 0)
            *reinterpret_cast<float4v*>(rawf + (16 * nt + l15) * 4) = dv;
    }
    asm volatile("s_waitcnt lgkmcnt(0)" ::: "memory");   // cross-lane raw routing

    // ---- volume rendering (per sample; DPP scans) ----
    float4v raw = *reinterpret_cast<const float4v*>(rawf + lane * 4);
    float r0 = raw[0], r1 = raw[1], r2 = raw[2], r3 = raw[3];

    float sigma = fmaxf(r0, 0.0f) + __logf(1.0f + __expf(-fabsf(r0)));
    float c0 = __builtin_amdgcn_rcpf(1.0f + __expf(-r1));
    float c1 = __builtin_amdgcn_rcpf(1.0f + __expf(-r2));
    float c2 = __builtin_amdgcn_rcpf(1.0f + __expf(-r3));
    float delta = (s == NS - 1) ? 0.5f * step : step;
    float sa = sigma * delta;

    float cum = scan32(sa);
    float Tprev = __expf(-(cum - sa));
    float w = Tprev * (1.0f - __expf(-sa));
    float rr = scan32(w * c0);
    float rg = scan32(w * c1);
    float rb = scan32(w * c2);

    if (s == NS - 1) {                         // lane 31/63 holds the totals
        int pix = blockIdx.x * 8 + lp;
        float alpha = 1.0f - __expf(-cum);
        float o0 = rr, o1 = rg, o2 = rb;
        if (hitf == 0.0f) { o0 = 0.0f; o1 = 0.0f; o2 = 0.0f; alpha = 0.0f; }
        out[0 * NPIX + pix] = o0;
        out[1 * NPIX + pix] = o1;
        out[2 * NPIX + pix] = o2;
        out[3 * NPIX + pix] = alpha;
    }
}

extern "C" void kernel_launch(void* const* d_in, const int* in_sizes, int n_in,
                              void* d_out, int out_size, void* d_ws, size_t ws_size,
                              hipStream_t stream) {
    const float* Kmat = (const float*)d_in[0];
    const float* Twc  = (const float*)d_in[1];
    const float* amn  = (const float*)d_in[2];
    const float* amx  = (const float*)d_in[3];
    const float* W1   = (const float*)d_in[4];
    const float* b1   = (const float*)d_in[5];
    const float* W2   = (const float*)d_in[6];
    const float* b2   = (const float*)d_in[7];
    const float* W3   = (const float*)d_in[8];
    const float* b3   = (const float*)d_in[9];
    float* out = (float*)d_out;
    short* ws  = (short*)d_ws;   // 15360 B used

    prep<<<1, 256, 0, stream>>>(W1, b1, W2, W3, b3, b2, ws);

    int blocks = NPIX * NS / 256;   // 12,800
    nerf_reg2<<<blocks, 256, 0, stream>>>(Kmat, Twc, amn, amx, ws, out);
}